// Round 10
// baseline (565.931 us; speedup 1.0000x reference)
//
#include <hip/hip_runtime.h>
#include <hip/hip_bf16.h>

typedef unsigned short u16;
typedef unsigned char u8;
typedef unsigned int u32;
typedef __attribute__((ext_vector_type(8))) short short8;
typedef __attribute__((ext_vector_type(4))) float f32x4;

#define NN 8192
#define KIN 256
#define FOUT 128
#define L2E 1.4426950408889634f

__device__ __forceinline__ float exp2fast(float x) { return __builtin_amdgcn_exp2f(x); }

__device__ __forceinline__ u16 f2bf(float f) {
    u32 u = __float_as_uint(f);
    u32 r = ((u >> 16) & 1u) + 0x7fffu;
    return (u16)((u + r) >> 16);
}
__device__ __forceinline__ u32 pk_bf16(float a, float b) {
    union { __hip_bfloat162 h2; u32 u; } cv;
    cv.h2 = __float22bfloat162_rn(make_float2(a, b));
    return cv.u;
}
__device__ __forceinline__ u32 fkey(float f) {
    u32 b = __float_as_uint(f);
    return (b & 0x80000000u) ? ~b : (b | 0x80000000u);
}
__device__ __forceinline__ float funkey(u32 k) {
    u32 b = (k & 0x80000000u) ? (k & 0x7fffffffu) : ~k;
    return __uint_as_float(b);
}

// ---------------- K1: Wh = h@W (fp32 acc) -> whfrag (B-fragment-major bf16), src, dst*log2e, gmax
// whfrag: [(kstep*8 + ntile)*64 + lane]*8 u16, elem j = Wh[kstep*32+(lane>>4)*8+j][ntile*16+(lane&15)]
__global__ __launch_bounds__(256) void k1_wh(
    const float* __restrict__ h, const float* __restrict__ W, const float* __restrict__ a,
    u16* __restrict__ whfrag,
    float* __restrict__ src, float* __restrict__ dl2e, u32* __restrict__ gmaxk)
{
    __shared__ float hT[64][36];
    __shared__ u16   lt[128][40];
    __shared__ float sd[32][2];
    const int t  = threadIdx.x;
    const int m0 = blockIdx.x * 32;
    const int rq = t >> 5, cq = t & 31;

    float acc[4][4];
#pragma unroll
    for (int i = 0; i < 4; i++)
#pragma unroll
        for (int j = 0; j < 4; j++) acc[i][j] = 0.f;
    if (t < 64) sd[t >> 1][t & 1] = 0.f;

    for (int kt = 0; kt < KIN; kt += 64) {
        __syncthreads();
#pragma unroll
        for (int s2 = 0; s2 < 2; s2++) {
            int f = s2 * 256 + t;
            int r = f >> 4, kc = (f & 15) * 4;
            float4 hv = *(const float4*)(h + (size_t)(m0 + r) * KIN + kt + kc);
            hT[kc + 0][r] = hv.x; hT[kc + 1][r] = hv.y;
            hT[kc + 2][r] = hv.z; hT[kc + 3][r] = hv.w;
        }
        __syncthreads();
        for (int k = 0; k < 64; k++) {
            float4 wv = *(const float4*)(W + (size_t)(kt + k) * FOUT + cq * 4);
            float h0 = hT[k][rq * 4 + 0], h1 = hT[k][rq * 4 + 1];
            float h2 = hT[k][rq * 4 + 2], h3 = hT[k][rq * 4 + 3];
            acc[0][0] += h0 * wv.x; acc[0][1] += h0 * wv.y; acc[0][2] += h0 * wv.z; acc[0][3] += h0 * wv.w;
            acc[1][0] += h1 * wv.x; acc[1][1] += h1 * wv.y; acc[1][2] += h1 * wv.z; acc[1][3] += h1 * wv.w;
            acc[2][0] += h2 * wv.x; acc[2][1] += h2 * wv.y; acc[2][2] += h2 * wv.z; acc[2][3] += h2 * wv.w;
            acc[3][0] += h3 * wv.x; acc[3][1] += h3 * wv.y; acc[3][2] += h3 * wv.z; acc[3][3] += h3 * wv.w;
        }
    }
#pragma unroll
    for (int i = 0; i < 4; i++) {
        float sp = 0.f, dp = 0.f;
#pragma unroll
        for (int j = 0; j < 4; j++) {
            sp += acc[i][j] * a[cq * 4 + j];
            dp += acc[i][j] * a[FOUT + cq * 4 + j];
            lt[cq * 4 + j][rq * 4 + i] = f2bf(acc[i][j]);
        }
        atomicAdd(&sd[rq * 4 + i][0], sp);
        atomicAdd(&sd[rq * 4 + i][1], dp);
    }
    __syncthreads();
    if (t < 32) { src[m0 + t] = sd[t][0]; dl2e[m0 + t] = sd[t][1] * L2E; }
    if (t < 64) {
        float v = (t < 32) ? sd[t][1] : -3.0e38f;
#pragma unroll
        for (int off = 32; off >= 1; off >>= 1) v = fmaxf(v, __shfl_down(v, off));
        if (t == 0) atomicMax(gmaxk, fkey(v));
    }
    const int kstep = blockIdx.x;
#pragma unroll
    for (int p = 0; p < 2; p++) {
        int f = p * 256 + t;
        int nt = f >> 6;
        int l  = f & 63;
        short8 v = *(const short8*)&lt[nt * 16 + (l & 15)][(l >> 4) * 8];
        *(short8*)(whfrag + ((size_t)(kstep * 8 + nt) * 64 + l) * 8) = v;
    }
}

// ---------------- K2a: streaming softmax-numerator pass (k0-shaped) -----------------
// Thread = (row i, col-quad c): sequential int4 adj read, 4 exps, 8B write of P in
// MFMA A-fragment-major layout. Wave-reduce + 1 atomic for exact row sums.
// Pfrag u16 index: (mt*256 + ks)*512 + l*8 + e  with mt=i>>4, ks=c>>3,
// l=(i&15)+16*((c>>1)&3), e=(c&1)*4  ->  k2c lane reads contiguous 16B.
__global__ __launch_bounds__(256) void k2a_p(
    const int* __restrict__ adj, const float* __restrict__ src, const float* __restrict__ dl2e,
    const u32* __restrict__ gmaxk, u16* __restrict__ pfrag, float* __restrict__ rsum)
{
    const size_t idx = (size_t)blockIdx.x * 256 + threadIdx.x;  // over N*N/4
    const int i = (int)(idx >> 11);
    const int c = (int)(idx & 2047);

    float s = src[i] * L2E;
    float gm = funkey(*gmaxk) * L2E;
    float xm = s + gm;
    float C = fmaxf(xm, 0.01f * xm);
    float y1 = s - C, y2 = 0.01f * s - C;

    int4 av = *(const int4*)(adj + idx * 4);
    float4 d = *(const float4*)(dl2e + c * 4);

    float x, p0, p1, p2, p3;
    x = fmaxf(y1 + d.x, y2 + 0.01f * d.x); p0 = exp2fast(av.x > 0 ? x : -1.0e9f);
    x = fmaxf(y1 + d.y, y2 + 0.01f * d.y); p1 = exp2fast(av.y > 0 ? x : -1.0e9f);
    x = fmaxf(y1 + d.z, y2 + 0.01f * d.z); p2 = exp2fast(av.z > 0 ? x : -1.0e9f);
    x = fmaxf(y1 + d.w, y2 + 0.01f * d.w); p3 = exp2fast(av.w > 0 ? x : -1.0e9f);

    // fragment-major 8B store
    {
        int mt = i >> 4, ks = c >> 3;
        int l = (i & 15) + ((c >> 1) & 3) * 16;
        int e = (c & 1) * 4;
        uint2 w = make_uint2(pk_bf16(p0, p1), pk_bf16(p2, p3));
        *(uint2*)(pfrag + ((size_t)(mt * 256 + ks) * 512 + l * 8 + e)) = w;
    }

    // exact row sum: wave covers 256 consecutive cols of ONE row (2048 % 64 == 0)
    float v = ((p0 + p1) + (p2 + p3));
    v += __shfl_down(v, 32); v += __shfl_down(v, 16); v += __shfl_down(v, 8);
    v += __shfl_down(v, 4);  v += __shfl_down(v, 2);  v += __shfl_down(v, 1);
    if ((threadIdx.x & 63) == 0) atomicAdd(&rsum[i], v);
}

// ---------------- K2c: fragment-stream GEMM out = (P@Whb) / rsum --------------------
// Block = one 16-row m-tile; 4 waves split K (2048 each); no LDS/barrier in K-loop.
// All loads are contiguous 1KB/wave runs (pfrag A + whfrag B).
__global__ __launch_bounds__(256, 4) void k2c_gemm(
    const u16* __restrict__ pfrag, const u16* __restrict__ whfrag,
    const float* __restrict__ rsum, float* __restrict__ out)
{
    __shared__ float ex[4][16][FOUT];            // 32 KB combine buffer
    const int t = threadIdx.x;
    const int lane = t & 63, wave = t >> 6;
    const int mt = blockIdx.x;                   // 0..511
    const int i0 = mt * 16;
    const int l15 = lane & 15, quad = lane >> 4;

    f32x4 acc[8];
#pragma unroll
    for (int nt = 0; nt < 8; nt++) acc[nt] = {0.f, 0.f, 0.f, 0.f};

    const u16* ap = pfrag + ((size_t)mt * 256 + wave * 64) * 512 + lane * 8;
    // depth-2 A prefetch
    uint4 a0 = *(const uint4*)ap;
    uint4 a1 = *(const uint4*)(ap + 512);

    for (int kk = 0; kk < 64; ++kk) {
        const int ks = wave * 64 + kk;
        uint4 bv[8];
        const u16* wf = whfrag + ((size_t)ks * 8 * 64 + lane) * 8;
#pragma unroll
        for (int nt = 0; nt < 8; nt++)
            bv[nt] = *(const uint4*)(wf + (size_t)nt * 64 * 8);

        uint4 av = a0;
        a0 = a1;
        if (kk + 2 < 64) a1 = *(const uint4*)(ap + (size_t)(kk + 2) * 512);

        union { uint4 q; short8 s8; } af; af.q = av;
#pragma unroll
        for (int nt = 0; nt < 8; nt++) {
            union { uint4 q; short8 s8; } bf; bf.q = bv[nt];
            acc[nt] = __builtin_amdgcn_mfma_f32_16x16x32_bf16(af.s8, bf.s8, acc[nt], 0, 0, 0);
        }
    }

    // combine 4 K-split waves + normalize (C/D: col=lane&15, row=quad*4+reg)
    {
        int crow = quad * 4, ccol = l15;
#pragma unroll
        for (int nt = 0; nt < 8; nt++)
#pragma unroll
            for (int reg = 0; reg < 4; reg++)
                ex[wave][crow + reg][nt * 16 + ccol] = acc[nt][reg];
    }
    __syncthreads();
    {
        int row = t >> 4, c8 = (t & 15) * 8;
        float s[8];
#pragma unroll
        for (int j = 0; j < 8; j++) s[j] = 0.f;
#pragma unroll
        for (int w = 0; w < 4; w++) {
            float4 v0 = *(const float4*)&ex[w][row][c8];
            float4 v1 = *(const float4*)&ex[w][row][c8 + 4];
            s[0] += v0.x; s[1] += v0.y; s[2] += v0.z; s[3] += v0.w;
            s[4] += v1.x; s[5] += v1.y; s[6] += v1.z; s[7] += v1.w;
        }
        float ri = 1.0f / rsum[i0 + row];
        float* op = out + (size_t)(i0 + row) * FOUT + c8;
        *(float4*)op       = make_float4(s[0] * ri, s[1] * ri, s[2] * ri, s[3] * ri);
        *(float4*)(op + 4) = make_float4(s[4] * ri, s[5] * ri, s[6] * ri, s[7] * ri);
    }
}

extern "C" void kernel_launch(void* const* d_in, const int* in_sizes, int n_in,
                              void* d_out, int out_size, void* d_ws, size_t ws_size,
                              hipStream_t stream) {
    const float* h   = (const float*)d_in[0];
    const int*   adj = (const int*)d_in[1];
    const float* W   = (const float*)d_in[2];
    const float* a   = (const float*)d_in[3];
    float* out = (float*)d_out;

    char* ws = (char*)d_ws;
    u16*   whfrag = (u16*)ws;                           // 2 MB
    float* src    = (float*)(ws + (2u << 20));          // 32 KB
    float* dl2e   = src + NN;                           // 32 KB
    float* rsum   = dl2e + NN;                          // 32 KB
    u32*   gmaxk  = (u32*)(rsum + NN);                  // 4 B
    u16*   pfrag  = (u16*)(ws + (16u << 20));           // 128 MB

    (void)hipMemsetAsync(gmaxk, 0, sizeof(u32), stream);
    (void)hipMemsetAsync(rsum, 0, NN * sizeof(float), stream);
    k1_wh<<<dim3(NN / 32), dim3(256), 0, stream>>>(h, W, a, whfrag, src, dl2e, gmaxk);
    k2a_p<<<dim3((NN / 4) * (NN / 256)), dim3(256), 0, stream>>>(adj, src, dl2e, gmaxk, pfrag, rsum);
    k2c_gemm<<<dim3(NN / 16), dim3(256), 0, stream>>>(pfrag, whfrag, rsum, out);
}

// Round 11
// 485.501 us; speedup vs baseline: 1.1657x; 1.1657x over previous
//
#include <hip/hip_runtime.h>
#include <hip/hip_bf16.h>

typedef unsigned short u16;
typedef unsigned char u8;
typedef unsigned int u32;
typedef __attribute__((ext_vector_type(8))) short short8;
typedef __attribute__((ext_vector_type(4))) float f32x4;

#define NN 8192
#define KIN 256
#define FOUT 128
#define L2E 1.4426950408889634f

__device__ __forceinline__ float exp2fast(float x) { return __builtin_amdgcn_exp2f(x); }

__device__ __forceinline__ u16 f2bf(float f) {
    u32 u = __float_as_uint(f);
    u32 r = ((u >> 16) & 1u) + 0x7fffu;
    return (u16)((u + r) >> 16);
}
__device__ __forceinline__ u32 pk_bf16(float a, float b) {
    union { __hip_bfloat162 h2; u32 u; } cv;
    cv.h2 = __float22bfloat162_rn(make_float2(a, b));
    return cv.u;
}
__device__ __forceinline__ u32 fkey(float f) {
    u32 b = __float_as_uint(f);
    return (b & 0x80000000u) ? ~b : (b | 0x80000000u);
}
__device__ __forceinline__ float funkey(u32 k) {
    u32 b = (k & 0x80000000u) ? (k & 0x7fffffffu) : ~k;
    return __uint_as_float(b);
}

// ---------------- K1: Wh = h@W (fp32 acc) -> whfrag (B-fragment-major bf16), src, dst*log2e, gmax
// whfrag: [(ks*8 + ntile)*64 + lane]*8 u16, elem j = Wh[ks*32+(lane>>4)*8+j][ntile*16+(lane&15)]
__global__ __launch_bounds__(256) void k1_wh(
    const float* __restrict__ h, const float* __restrict__ W, const float* __restrict__ a,
    u16* __restrict__ whfrag,
    float* __restrict__ src, float* __restrict__ dl2e, u32* __restrict__ gmaxk)
{
    __shared__ float hT[64][36];
    __shared__ u16   lt[128][40];
    __shared__ float sd[32][2];
    const int t  = threadIdx.x;
    const int m0 = blockIdx.x * 32;
    const int rq = t >> 5, cq = t & 31;

    float acc[4][4];
#pragma unroll
    for (int i = 0; i < 4; i++)
#pragma unroll
        for (int j = 0; j < 4; j++) acc[i][j] = 0.f;
    if (t < 64) sd[t >> 1][t & 1] = 0.f;

    for (int kt = 0; kt < KIN; kt += 64) {
        __syncthreads();
#pragma unroll
        for (int s2 = 0; s2 < 2; s2++) {
            int f = s2 * 256 + t;
            int r = f >> 4, kc = (f & 15) * 4;
            float4 hv = *(const float4*)(h + (size_t)(m0 + r) * KIN + kt + kc);
            hT[kc + 0][r] = hv.x; hT[kc + 1][r] = hv.y;
            hT[kc + 2][r] = hv.z; hT[kc + 3][r] = hv.w;
        }
        __syncthreads();
        for (int k = 0; k < 64; k++) {
            float4 wv = *(const float4*)(W + (size_t)(kt + k) * FOUT + cq * 4);
            float h0 = hT[k][rq * 4 + 0], h1 = hT[k][rq * 4 + 1];
            float h2 = hT[k][rq * 4 + 2], h3 = hT[k][rq * 4 + 3];
            acc[0][0] += h0 * wv.x; acc[0][1] += h0 * wv.y; acc[0][2] += h0 * wv.z; acc[0][3] += h0 * wv.w;
            acc[1][0] += h1 * wv.x; acc[1][1] += h1 * wv.y; acc[1][2] += h1 * wv.z; acc[1][3] += h1 * wv.w;
            acc[2][0] += h2 * wv.x; acc[2][1] += h2 * wv.y; acc[2][2] += h2 * wv.z; acc[2][3] += h2 * wv.w;
            acc[3][0] += h3 * wv.x; acc[3][1] += h3 * wv.y; acc[3][2] += h3 * wv.z; acc[3][3] += h3 * wv.w;
        }
    }
#pragma unroll
    for (int i = 0; i < 4; i++) {
        float sp = 0.f, dp = 0.f;
#pragma unroll
        for (int j = 0; j < 4; j++) {
            sp += acc[i][j] * a[cq * 4 + j];
            dp += acc[i][j] * a[FOUT + cq * 4 + j];
            lt[cq * 4 + j][rq * 4 + i] = f2bf(acc[i][j]);
        }
        atomicAdd(&sd[rq * 4 + i][0], sp);
        atomicAdd(&sd[rq * 4 + i][1], dp);
    }
    __syncthreads();
    if (t < 32) { src[m0 + t] = sd[t][0]; dl2e[m0 + t] = sd[t][1] * L2E; }
    if (t < 64) {
        float v = (t < 32) ? sd[t][1] : -3.0e38f;
#pragma unroll
        for (int off = 32; off >= 1; off >>= 1) v = fmaxf(v, __shfl_down(v, off));
        if (t == 0) atomicMax(gmaxk, fkey(v));
    }
    const int kstep = blockIdx.x;
#pragma unroll
    for (int p = 0; p < 2; p++) {
        int f = p * 256 + t;
        int nt = f >> 6;
        int l  = f & 63;
        short8 v = *(const short8*)&lt[nt * 16 + (l & 15)][(l >> 4) * 8];
        *(short8*)(whfrag + ((size_t)(kstep * 8 + nt) * 64 + l) * 8) = v;
    }
}

// ---------------- K0t: adj -> consumer-ordered mask map (bmt) -----------------------
// bmt u16 at [mt*16384 + ks*64 + lane]: lane = l15 + 16*q covers row mt*16+l15,
// cols ks*32 + q*8 .. +7 (byte0 = cols+0..3 bits0-3, byte1 = cols+4..7 bits0-3).
// Block = one mt: streams 16 full 8KB rows sequentially, stages in LDS, writes 32KB
// contiguous. Reads: 2KB/wave runs. LDS both directions <=2-way conflicts.
__global__ __launch_bounds__(256) void k0t_pack(const int* __restrict__ adj,
                                               u16* __restrict__ bmt)
{
    __shared__ u16 st[16][1024];                 // 32 KB: [row][t' = cb/2]
    const int t = threadIdx.x;
    const int mt = blockIdx.x;
    const int i0 = mt * 16;

    for (int r = 0; r < 16; r++) {
        const int* ap = adj + (size_t)(i0 + r) * NN;
#pragma unroll
        for (int it = 0; it < 4; it++) {
            int tp = it * 256 + t;               // 0..1023, covers cols tp*8..tp*8+7
            int4 va = *(const int4*)(ap + tp * 8);
            int4 vb = *(const int4*)(ap + tp * 8 + 4);
            u32 b0 = (u32)((va.x > 0) | ((va.y > 0) << 1) | ((va.z > 0) << 2) | ((va.w > 0) << 3));
            u32 b1 = (u32)((vb.x > 0) | ((vb.y > 0) << 1) | ((vb.z > 0) << 2) | ((vb.w > 0) << 3));
            st[r][tp] = (u16)(b0 | (b1 << 8));
        }
    }
    __syncthreads();
    // gather-transpose out: thread t writes 64 consecutive u16 (G = t*64 + i)
    // source LDS idx: row = G&15, t' = (G>>6)*4 + ((G>>4)&3)
    u16* op = bmt + (size_t)mt * 16384 + t * 64;
#pragma unroll
    for (int v4 = 0; v4 < 8; v4++) {             // 8 x uint4 = 64 u16
        u16 tmp[8];
#pragma unroll
        for (int j = 0; j < 8; j++) {
            int G = t * 64 + v4 * 8 + j;
            tmp[j] = st[G & 15][((G >> 6) << 2) + ((G >> 4) & 3)];
        }
        *(uint4*)(op + v4 * 8) = *(const uint4*)tmp;
    }
}

// ---------------- K2: minimal-chain consumer --------------------------------------
// Block = 16 rows x full K; wave w owns K-window w*2048 (ks w*64..w*64+63).
// Lane (l15=row, quad=k-subblock): P built directly in A-fragment registers; masks
// from bmt (contiguous 128B/wave/iter); B straight from whfrag. No LDS/barriers in
// the K-loop. One barrier for the 4-wave combine + normalize.
__global__ __launch_bounds__(256, 4) void k2_attn(
    const u16* __restrict__ bmt, const float* __restrict__ src, const float* __restrict__ dl2e,
    const u16* __restrict__ whfrag, const u32* __restrict__ gmaxk,
    float* __restrict__ out)
{
    __shared__ float ex[4][16][FOUT];            // 32 KB combine
    __shared__ float pf[4][16];
    const int t = threadIdx.x;
    const int lane = t & 63, wave = t >> 6;
    const int mt = blockIdx.x;
    const int i0 = mt * 16;
    const int l15 = lane & 15, quad = lane >> 4;

    // row constants (row = i0 + l15)
    const float gm = funkey(*gmaxk) * L2E;
    float s = src[i0 + l15] * L2E;
    float xm = s + gm;
    float C = fmaxf(xm, 0.01f * xm);
    const float y1 = s - C, y2 = 0.01f * s - C;

    f32x4 acc[8];
#pragma unroll
    for (int nt = 0; nt < 8; nt++) acc[nt] = {0.f, 0.f, 0.f, 0.f};
    float psum = 0.f;

    const u16* bp = bmt + (size_t)mt * 16384 + (wave * 64) * 64 + lane;
    const int ks0 = wave * 64;

    // depth-2 prefetch of mask + d
    u16 mv[2]; float4 dA[2], dB[2];
#pragma unroll
    for (int s2 = 0; s2 < 2; s2++) {
        mv[s2] = bp[s2 * 64];
        dA[s2] = *(const float4*)(dl2e + (ks0 + s2) * 32 + quad * 8);
        dB[s2] = *(const float4*)(dl2e + (ks0 + s2) * 32 + quad * 8 + 4);
    }

#pragma unroll 4
    for (int kk = 0; kk < 64; ++kk) {
        const int sl = kk & 1;
        const int ksg = ks0 + kk;

        // B fragments (L2), issued first
        uint4 bv[8];
        const u16* wf = whfrag + ((size_t)(ksg * 8) * 64 + lane) * 8;
#pragma unroll
        for (int nt = 0; nt < 8; nt++)
            bv[nt] = *(const uint4*)(wf + (size_t)nt * 64 * 8);

        u32 m = mv[sl];
        float4 d1 = dA[sl], d2 = dB[sl];

        float x, p0, p1, p2, p3, p4, p5, p6, p7;
        x = fmaxf(y1 + d1.x, y2 + 0.01f * d1.x); p0 = exp2fast((m & 0x001u) ? x : -1.0e9f);
        x = fmaxf(y1 + d1.y, y2 + 0.01f * d1.y); p1 = exp2fast((m & 0x002u) ? x : -1.0e9f);
        x = fmaxf(y1 + d1.z, y2 + 0.01f * d1.z); p2 = exp2fast((m & 0x004u) ? x : -1.0e9f);
        x = fmaxf(y1 + d1.w, y2 + 0.01f * d1.w); p3 = exp2fast((m & 0x008u) ? x : -1.0e9f);
        x = fmaxf(y1 + d2.x, y2 + 0.01f * d2.x); p4 = exp2fast((m & 0x100u) ? x : -1.0e9f);
        x = fmaxf(y1 + d2.y, y2 + 0.01f * d2.y); p5 = exp2fast((m & 0x200u) ? x : -1.0e9f);
        x = fmaxf(y1 + d2.z, y2 + 0.01f * d2.z); p6 = exp2fast((m & 0x400u) ? x : -1.0e9f);
        x = fmaxf(y1 + d2.w, y2 + 0.01f * d2.w); p7 = exp2fast((m & 0x800u) ? x : -1.0e9f);
        psum += ((p0 + p1) + (p2 + p3)) + ((p4 + p5) + (p6 + p7));

        // prefetch kk+2
        if (kk + 2 < 64) {
            mv[sl] = bp[(kk + 2) * 64];
            dA[sl] = *(const float4*)(dl2e + (ksg + 2) * 32 + quad * 8);
            dB[sl] = *(const float4*)(dl2e + (ksg + 2) * 32 + quad * 8 + 4);
        }

        union { short8 s8; u32 u[4]; } af;
        af.u[0] = pk_bf16(p0, p1); af.u[1] = pk_bf16(p2, p3);
        af.u[2] = pk_bf16(p4, p5); af.u[3] = pk_bf16(p6, p7);

#pragma unroll
        for (int nt = 0; nt < 8; nt++) {
            union { uint4 q; short8 s8; } bf; bf.q = bv[nt];
            acc[nt] = __builtin_amdgcn_mfma_f32_16x16x32_bf16(af.s8, bf.s8, acc[nt], 0, 0, 0);
        }
    }

    // row-sum partial for this wave's window: reduce over 4 quads (stride 16)
    psum += __shfl_down(psum, 32);
    psum += __shfl_down(psum, 16);
    if (lane < 16) pf[wave][l15] = psum;

    // acc -> exchange (C/D: col=lane&15, row=quad*4+reg)
    {
        int crow = quad * 4, ccol = l15;
#pragma unroll
        for (int nt = 0; nt < 8; nt++)
#pragma unroll
            for (int reg = 0; reg < 4; reg++)
                ex[wave][crow + reg][nt * 16 + ccol] = acc[nt][reg];
    }
    __syncthreads();
    {
        int row = t >> 4, c8 = (t & 15) * 8;
        float sacc[8];
#pragma unroll
        for (int j = 0; j < 8; j++) sacc[j] = 0.f;
        float l = 0.f;
#pragma unroll
        for (int w = 0; w < 4; w++) {
            float4 v0 = *(const float4*)&ex[w][row][c8];
            float4 v1 = *(const float4*)&ex[w][row][c8 + 4];
            sacc[0] += v0.x; sacc[1] += v0.y; sacc[2] += v0.z; sacc[3] += v0.w;
            sacc[4] += v1.x; sacc[5] += v1.y; sacc[6] += v1.z; sacc[7] += v1.w;
            l += pf[w][row];
        }
        float ri = 1.0f / l;
        float* op = out + (size_t)(i0 + row) * FOUT + c8;
        *(float4*)op       = make_float4(sacc[0] * ri, sacc[1] * ri, sacc[2] * ri, sacc[3] * ri);
        *(float4*)(op + 4) = make_float4(sacc[4] * ri, sacc[5] * ri, sacc[6] * ri, sacc[7] * ri);
    }
}

extern "C" void kernel_launch(void* const* d_in, const int* in_sizes, int n_in,
                              void* d_out, int out_size, void* d_ws, size_t ws_size,
                              hipStream_t stream) {
    const float* h   = (const float*)d_in[0];
    const int*   adj = (const int*)d_in[1];
    const float* W   = (const float*)d_in[2];
    const float* a   = (const float*)d_in[3];
    float* out = (float*)d_out;

    char* ws = (char*)d_ws;
    u16*   whfrag = (u16*)ws;                           // 2 MB
    float* src    = (float*)(ws + (2u << 20));          // 32 KB
    float* dl2e   = src + NN;                           // 32 KB
    u32*   gmaxk  = (u32*)(dl2e + NN);                  // 4 B
    u16*   bmt    = (u16*)(ws + (3u << 20));            // 16 MB

    (void)hipMemsetAsync(gmaxk, 0, sizeof(u32), stream);
    k0t_pack<<<dim3(NN / 16), dim3(256), 0, stream>>>(adj, bmt);
    k1_wh<<<dim3(NN / 32), dim3(256), 0, stream>>>(h, W, a, whfrag, src, dl2e, gmaxk);
    k2_attn<<<dim3(NN / 16), dim3(256), 0, stream>>>(bmt, src, dl2e, whfrag, gmaxk, out);
}